// Round 1
// baseline (174.718 us; speedup 1.0000x reference)
//
#include <hip/hip_runtime.h>
#include <hip/hip_bf16.h>
#include <stdint.h>

#define N_TOT 8192
#define BSZ   4096
#define KEXT  384           // 3*128: A=[hi|hi|lo], B=[hi|lo|hi]
#define NB    64            // 8192/128 tiles per dimension

typedef __attribute__((ext_vector_type(8))) short bf16x8;
typedef __attribute__((ext_vector_type(4))) float f32x4;

// ---------------- prep: f32 -> hi/lo bf16 split, build P and Q ----------------
__global__ __launch_bounds__(256) void prep_kernel(
    const float* __restrict__ feat,
    __hip_bfloat16* __restrict__ P, __hip_bfloat16* __restrict__ Q) {
  int idx = blockIdx.x * 256 + threadIdx.x;       // 0 .. 8192*128-1
  int r = idx >> 7, d = idx & 127;
  int b = r & (BSZ - 1), v = r >> 12;             // cf row r = features[b, v, :], r = v*BSZ+b
  float x = feat[(((b << 1) + v) << 7) + d];
  __hip_bfloat16 hi = __float2bfloat16(x);
  float hif = __bfloat162float(hi);
  __hip_bfloat16 lo = __float2bfloat16(x - hif);
  size_t base = (size_t)r * KEXT;
  P[base + d] = hi; P[base + 128 + d] = hi; P[base + 256 + d] = lo;
  Q[base + d] = hi; Q[base + 128 + d] = lo; Q[base + 256 + d] = hi;
}

// ---------------- label histogram (labels in [0,100)) ----------------
__global__ __launch_bounds__(256) void hist_kernel(const int* __restrict__ labels,
                                                   int* __restrict__ cnt) {
  __shared__ int h[128];
  if (threadIdx.x < 128) h[threadIdx.x] = 0;
  __syncthreads();
  for (int i = threadIdx.x; i < BSZ; i += 256) atomicAdd(&h[labels[i] & 127], 1);
  __syncthreads();
  if (threadIdx.x < 128) cnt[threadIdx.x] = h[threadIdx.x];
}

// ---------------- fused Gram GEMM + per-row online max/expsum partials ----------------
// C[i][j] = sum_k P[i][k]*Q[j][k]  (M=N=8192, K=384), 128x128 tile, BK=64, 4 waves.
// Epilogue: v = (labR!=labC) ? C*20 : 0 ; per-row (max, sum exp(v-max)) over the
// tile's 128 columns -> partial (m,s) at pM/pS[bc*8192 + row].
__global__ __launch_bounds__(256) void gemm_kernel(
    const __hip_bfloat16* __restrict__ P, const __hip_bfloat16* __restrict__ Q,
    const int* __restrict__ labels,
    float* __restrict__ pM, float* __restrict__ pS) {
  __shared__ __align__(16) __hip_bfloat16 ldsA[128 * 64];
  __shared__ __align__(16) __hip_bfloat16 ldsB[128 * 64];
  __shared__ int labR[128], labC[128];
  __shared__ float redM[2][128], redS[2][128];

  // bijective XCD-aware swizzle (nwg=4096, 4096%8==0)
  int orig = blockIdx.x;
  int wg = (orig & 7) * 512 + (orig >> 3);
  int br = wg >> 6, bc = wg & 63;

  int tid = threadIdx.x;
  int lane = tid & 63, wave = tid >> 6;
  int wr = wave >> 1, wc = wave & 1;

  if (tid < 128) {
    labR[tid] = labels[(br * 128 + tid) & (BSZ - 1)];
    labC[tid] = labels[(bc * 128 + tid) & (BSZ - 1)];
  }

  f32x4 acc[4][4];
#pragma unroll
  for (int m = 0; m < 4; ++m)
#pragma unroll
    for (int n = 0; n < 4; ++n) acc[m][n] = f32x4{0.f, 0.f, 0.f, 0.f};

  int srow = lane >> 3;        // row-within-8 for staging
  int cs = lane & 7;           // 16B chunk slot this lane fills (linear LDS dest)

  for (int kt = 0; kt < 6; ++kt) {
    // ---- stage A,B tiles: linear LDS dest + inverse-XOR-swizzled global source ----
#pragma unroll
    for (int rnd = 0; rnd < 4; ++rnd) {
      int row = rnd * 32 + wave * 8 + srow;
      int cl = cs ^ (row & 7);  // logical 16B chunk fetched into store slot cs
      const __hip_bfloat16* ga = P + (size_t)(br * 128 + row) * KEXT + kt * 64 + cl * 8;
      const __hip_bfloat16* gb = Q + (size_t)(bc * 128 + row) * KEXT + kt * 64 + cl * 8;
      char* la = (char*)ldsA + rnd * 4096 + wave * 1024;   // wave-uniform base, +lane*16 implicit
      char* lb = (char*)ldsB + rnd * 4096 + wave * 1024;
      __builtin_amdgcn_global_load_lds((const __attribute__((address_space(1))) void*)ga,
                                       (__attribute__((address_space(3))) void*)la, 16, 0, 0);
      __builtin_amdgcn_global_load_lds((const __attribute__((address_space(1))) void*)gb,
                                       (__attribute__((address_space(3))) void*)lb, 16, 0, 0);
    }
    __syncthreads();
    // ---- compute: 2 k-substeps of 32, 16 MFMA each ----
#pragma unroll
    for (int kk = 0; kk < 2; ++kk) {
      bf16x8 afr[4], bfr[4];
      int cb = kk * 4 + (lane >> 4);   // logical chunk index for this lane's k-slice
#pragma unroll
      for (int m = 0; m < 4; ++m) {
        int row = wr * 64 + m * 16 + (lane & 15);
        afr[m] = *(const bf16x8*)((const char*)ldsA + row * 128 + ((cb ^ (row & 7)) << 4));
      }
#pragma unroll
      for (int n = 0; n < 4; ++n) {
        int row = wc * 64 + n * 16 + (lane & 15);
        bfr[n] = *(const bf16x8*)((const char*)ldsB + row * 128 + ((cb ^ (row & 7)) << 4));
      }
#pragma unroll
      for (int m = 0; m < 4; ++m)
#pragma unroll
        for (int n = 0; n < 4; ++n)
          acc[m][n] = __builtin_amdgcn_mfma_f32_16x16x32_bf16(afr[m], bfr[n], acc[m][n], 0, 0, 0);
    }
    __syncthreads();
  }

  // ---- epilogue: mask, scale x20, per-row max & expsum over this tile ----
  int lc0 = labC[wc * 64 + 0 * 16 + (lane & 15)];
  int lc1 = labC[wc * 64 + 1 * 16 + (lane & 15)];
  int lc2 = labC[wc * 64 + 2 * 16 + (lane & 15)];
  int lc3 = labC[wc * 64 + 3 * 16 + (lane & 15)];

#pragma unroll
  for (int m = 0; m < 4; ++m) {
    int rowb = wr * 64 + m * 16 + ((lane >> 4) << 2);
#pragma unroll
    for (int reg = 0; reg < 4; ++reg) {
      int lr = labR[rowb + reg];
      float v0 = (lr != lc0) ? acc[m][0][reg] * 20.0f : 0.0f;
      float v1 = (lr != lc1) ? acc[m][1][reg] * 20.0f : 0.0f;
      float v2 = (lr != lc2) ? acc[m][2][reg] * 20.0f : 0.0f;
      float v3 = (lr != lc3) ? acc[m][3][reg] * 20.0f : 0.0f;
      float mx = fmaxf(fmaxf(v0, v1), fmaxf(v2, v3));
#pragma unroll
      for (int off = 1; off < 16; off <<= 1) mx = fmaxf(mx, __shfl_xor(mx, off, 64));
      float s = expf(v0 - mx) + expf(v1 - mx) + expf(v2 - mx) + expf(v3 - mx);
#pragma unroll
      for (int off = 1; off < 16; off <<= 1) s += __shfl_xor(s, off, 64);
      if ((lane & 15) == 0) { redM[wc][rowb + reg] = mx; redS[wc][rowb + reg] = s; }
    }
  }
  __syncthreads();
  if (tid < 128) {
    float m0 = redM[0][tid], m1 = redM[1][tid];
    float s0 = redS[0][tid], s1 = redS[1][tid];
    float M = fmaxf(m0, m1);
    float S = s0 * expf(m0 - M) + s1 * expf(m1 - M);
    int grow = br * 128 + tid;
    pM[(size_t)bc * N_TOT + grow] = M;   // chunk-major for coalesced reduce reads
    pS[(size_t)bc * N_TOT + grow] = S;
  }
}

// ---------------- combine 64 chunk-partials per row, partial-sum S per block ----------------
__global__ __launch_bounds__(256) void rowred_kernel(const float* __restrict__ pM,
                                                     const float* __restrict__ pS,
                                                     float* __restrict__ blockS) {
  int row = blockIdx.x * 256 + threadIdx.x;   // 32 blocks x 256 = 8192 rows
  float M = -3.0e38f;
  for (int c = 0; c < NB; ++c) M = fmaxf(M, pM[(size_t)c * N_TOT + row]);
  float s = 0.0f;
  for (int c = 0; c < NB; ++c)
    s += pS[(size_t)c * N_TOT + row] * expf(pM[(size_t)c * N_TOT + row] - M);
  __shared__ float red[256];
  red[threadIdx.x] = s;
  __syncthreads();
  for (int st = 128; st > 0; st >>= 1) {
    if (threadIdx.x < st) red[threadIdx.x] += red[threadIdx.x + st];
    __syncthreads();
  }
  if (threadIdx.x == 0) blockS[blockIdx.x] = red[0];
}

// ---------------- final scalar: S, N, validity -> loss ----------------
__global__ void final_kernel(const float* __restrict__ blockS, const int* __restrict__ cnt,
                             float* __restrict__ out) {
  int lane = threadIdx.x;              // 1 wave
  float s = (lane < 32) ? blockS[lane] : 0.0f;
#pragma unroll
  for (int off = 1; off < 64; off <<= 1) s += __shfl_xor(s, off, 64);
  if (lane == 0) {
    double Stot = (double)s;
    long long sumsq = 0;
    int nval = 0;
    for (int c = 0; c < 128; ++c) {
      long long cc = cnt[c];
      sumsq += cc * cc;
      if (cc > 0 && cc < BSZ) nval += 2 * (int)cc;   // valid rows iff not all labels equal
    }
    double Nd = (double)N_TOT * (double)N_TOT - 4.0 * (double)sumsq;
    float loss;
    if (Nd <= 0.0 || nval == 0) {
      loss = logf(1e-6f);              // all_zero branch: xv stays 0 -> log(eps)
    } else {
      float x = (float)(Stot / Nd);
      loss = ((float)nval * logf(x + 1e-6f) +
              (float)(N_TOT - nval) * logf(1e-6f)) / (float)N_TOT;
    }
    out[0] = loss;
  }
}

extern "C" void kernel_launch(void* const* d_in, const int* in_sizes, int n_in,
                              void* d_out, int out_size, void* d_ws, size_t ws_size,
                              hipStream_t stream) {
  const float* feat = (const float*)d_in[0];
  const int* labels = (const int*)d_in[1];
  float* out = (float*)d_out;

  char* ws = (char*)d_ws;
  __hip_bfloat16* P  = (__hip_bfloat16*)(ws);                     // 8192*384*2 = 6,291,456
  __hip_bfloat16* Q  = (__hip_bfloat16*)(ws + 6291456);           // 6,291,456
  float* pM          = (float*)(ws + 12582912);                   // 8192*64*4 = 2,097,152
  float* pS          = (float*)(ws + 14680064);                   // 2,097,152
  int* cnt           = (int*)(ws + 16777216);                     // 512
  float* blockS      = (float*)(ws + 16777728);                   // 128

  prep_kernel<<<4096, 256, 0, stream>>>(feat, P, Q);
  hist_kernel<<<1, 256, 0, stream>>>(labels, cnt);
  gemm_kernel<<<4096, 256, 0, stream>>>(P, Q, labels, pM, pS);
  rowred_kernel<<<32, 256, 0, stream>>>(pM, pS, blockS);
  final_kernel<<<1, 64, 0, stream>>>(blockS, cnt, out);
}

// Round 2
// 121.204 us; speedup vs baseline: 1.4415x; 1.4415x over previous
//
#include <hip/hip_runtime.h>
#include <hip/hip_bf16.h>
#include <stdint.h>

#define N_TOT 8192
#define BSZ   4096
#define KEXT  384           // 3*128: A=[hi|hi|lo], B=[hi|lo|hi]
#define NB    64            // 8192/128 tiles per dimension
#define NBLK_TRI 2080       // NB*(NB+1)/2 upper-triangle tiles
#define SCALE2 28.853900817779268f   // 20 * log2(e): work in base-2 domain

typedef __attribute__((ext_vector_type(8))) short bf16x8;
typedef __attribute__((ext_vector_type(4))) float f32x4;

// ---------------- prep: f32 -> hi/lo bf16 split, build P and Q; block 4096 = label hist ----------------
__global__ __launch_bounds__(256) void prep_kernel(
    const float* __restrict__ feat, const int* __restrict__ labels,
    __hip_bfloat16* __restrict__ P, __hip_bfloat16* __restrict__ Q,
    int* __restrict__ cnt) {
  if (blockIdx.x == 4096) {   // label histogram (labels in [0,100))
    __shared__ int h[128];
    if (threadIdx.x < 128) h[threadIdx.x] = 0;
    __syncthreads();
    for (int i = threadIdx.x; i < BSZ; i += 256) atomicAdd(&h[labels[i] & 127], 1);
    __syncthreads();
    if (threadIdx.x < 128) cnt[threadIdx.x] = h[threadIdx.x];
    return;
  }
  int idx = blockIdx.x * 256 + threadIdx.x;       // 0 .. 8192*128-1
  int r = idx >> 7, d = idx & 127;
  int b = r & (BSZ - 1), v = r >> 12;             // cf row r = features[b, v, :], r = v*BSZ+b
  float x = feat[(((b << 1) + v) << 7) + d];
  __hip_bfloat16 hi = __float2bfloat16(x);
  float hif = __bfloat162float(hi);
  __hip_bfloat16 lo = __float2bfloat16(x - hif);
  size_t base = (size_t)r * KEXT;
  P[base + d] = hi; P[base + 128 + d] = hi; P[base + 256 + d] = lo;
  Q[base + d] = hi; Q[base + 128 + d] = lo; Q[base + 256 + d] = hi;
}

// ---------------- fused Gram GEMM (triangular) + per-row AND per-col online max/exp2sum partials ----------------
// Tile (br,bc) with br<=bc. Row partials -> pM/pS[bc*N + br*128+i]; if br!=bc the
// transposed tile's row partials (= this tile's column partials) -> pM/pS[br*N + bc*128+j].
__global__ __launch_bounds__(256) void gemm_kernel(
    const __hip_bfloat16* __restrict__ P, const __hip_bfloat16* __restrict__ Q,
    const int* __restrict__ labels,
    float* __restrict__ pM, float* __restrict__ pS) {
  __shared__ __align__(16) __hip_bfloat16 ldsA[128 * 64];
  __shared__ __align__(16) __hip_bfloat16 ldsB[128 * 64];
  __shared__ int labR[128], labC[128];
  __shared__ float redM[2][128], redS[2][128];
  __shared__ float redCM[2][128], redCS[2][128];

  // bijective XCD-aware swizzle (2080 = 8*260)
  int orig = blockIdx.x;
  int wg = (orig & 7) * 260 + (orig >> 3);
  // triangular decode: wg -> (br, bc), br<=bc
  int br = 0, rem = wg;
  while (rem >= (NB - br)) { rem -= (NB - br); ++br; }
  int bc = br + rem;

  int tid = threadIdx.x;
  int lane = tid & 63, wave = tid >> 6;
  int wr = wave >> 1, wc = wave & 1;
  int lq = lane >> 4, lr16 = lane & 15;

  if (tid < 128) {
    labR[tid] = labels[(br * 128 + tid) & (BSZ - 1)];
    labC[tid] = labels[(bc * 128 + tid) & (BSZ - 1)];
  }

  f32x4 acc[4][4];
#pragma unroll
  for (int m = 0; m < 4; ++m)
#pragma unroll
    for (int n = 0; n < 4; ++n) acc[m][n] = f32x4{0.f, 0.f, 0.f, 0.f};

  int srow = lane >> 3;        // row-within-8 for staging
  int cs = lane & 7;           // 16B chunk slot this lane fills (linear LDS dest)

  for (int kt = 0; kt < 6; ++kt) {
    // ---- stage A,B tiles: linear LDS dest + inverse-XOR-swizzled global source ----
#pragma unroll
    for (int rnd = 0; rnd < 4; ++rnd) {
      int row = rnd * 32 + wave * 8 + srow;
      int cl = cs ^ (row & 7);  // logical 16B chunk fetched into store slot cs
      const __hip_bfloat16* ga = P + (size_t)(br * 128 + row) * KEXT + kt * 64 + cl * 8;
      const __hip_bfloat16* gb = Q + (size_t)(bc * 128 + row) * KEXT + kt * 64 + cl * 8;
      char* la = (char*)ldsA + rnd * 4096 + wave * 1024;   // wave-uniform base, +lane*16 implicit
      char* lb = (char*)ldsB + rnd * 4096 + wave * 1024;
      __builtin_amdgcn_global_load_lds((const __attribute__((address_space(1))) void*)ga,
                                       (__attribute__((address_space(3))) void*)la, 16, 0, 0);
      __builtin_amdgcn_global_load_lds((const __attribute__((address_space(1))) void*)gb,
                                       (__attribute__((address_space(3))) void*)lb, 16, 0, 0);
    }
    __syncthreads();
    // ---- compute: 2 k-substeps of 32, 16 MFMA each ----
#pragma unroll
    for (int kk = 0; kk < 2; ++kk) {
      bf16x8 afr[4], bfr[4];
      int cb = kk * 4 + (lane >> 4);   // logical chunk index for this lane's k-slice
#pragma unroll
      for (int m = 0; m < 4; ++m) {
        int row = wr * 64 + m * 16 + lr16;
        afr[m] = *(const bf16x8*)((const char*)ldsA + row * 128 + ((cb ^ (row & 7)) << 4));
      }
#pragma unroll
      for (int n = 0; n < 4; ++n) {
        int row = wc * 64 + n * 16 + lr16;
        bfr[n] = *(const bf16x8*)((const char*)ldsB + row * 128 + ((cb ^ (row & 7)) << 4));
      }
#pragma unroll
      for (int m = 0; m < 4; ++m)
#pragma unroll
        for (int n = 0; n < 4; ++n)
          acc[m][n] = __builtin_amdgcn_mfma_f32_16x16x32_bf16(afr[m], bfr[n], acc[m][n], 0, 0, 0);
    }
    __syncthreads();
  }

  // ---- epilogue: mask, scale (base-2 domain), per-row and per-col max & exp2-sum ----
  int lc[4];
#pragma unroll
  for (int n = 0; n < 4; ++n) lc[n] = labC[wc * 64 + n * 16 + lr16];

  // row pass: row = wr*64 + m*16 + lq*4 + reg; its 64 cols (this wc half) live across
  // n(4) x the 16 lanes of this lq-group.
#pragma unroll
  for (int m = 0; m < 4; ++m) {
    int rowb = wr * 64 + m * 16 + (lq << 2);
#pragma unroll
    for (int reg = 0; reg < 4; ++reg) {
      int lrv = labR[rowb + reg];
      float v0 = (lrv != lc[0]) ? acc[m][0][reg] * SCALE2 : 0.0f;
      float v1 = (lrv != lc[1]) ? acc[m][1][reg] * SCALE2 : 0.0f;
      float v2 = (lrv != lc[2]) ? acc[m][2][reg] * SCALE2 : 0.0f;
      float v3 = (lrv != lc[3]) ? acc[m][3][reg] * SCALE2 : 0.0f;
      float mx = fmaxf(fmaxf(v0, v1), fmaxf(v2, v3));
#pragma unroll
      for (int off = 1; off < 16; off <<= 1) mx = fmaxf(mx, __shfl_xor(mx, off, 64));
      float s = exp2f(v0 - mx) + exp2f(v1 - mx) + exp2f(v2 - mx) + exp2f(v3 - mx);
#pragma unroll
      for (int off = 1; off < 16; off <<= 1) s += __shfl_xor(s, off, 64);
      if (lr16 == 0) { redM[wc][rowb + reg] = mx; redS[wc][rowb + reg] = s; }
    }
  }

  // col pass (only off-diagonal tiles): col = wc*64 + n*16 + lr16; its 64 rows (this wr
  // half) live in-thread across m(4) x reg(4), then across lq groups (shfl 16,32).
  if (br != bc) {
#pragma unroll
    for (int n = 0; n < 4; ++n) {
      int lcn = lc[n];
      float cmx = -3.0e38f;
#pragma unroll
      for (int m = 0; m < 4; ++m) {
        int rowb = wr * 64 + m * 16 + (lq << 2);
#pragma unroll
        for (int reg = 0; reg < 4; ++reg) {
          float v = (labR[rowb + reg] != lcn) ? acc[m][n][reg] * SCALE2 : 0.0f;
          cmx = fmaxf(cmx, v);
        }
      }
      cmx = fmaxf(cmx, __shfl_xor(cmx, 16, 64));
      cmx = fmaxf(cmx, __shfl_xor(cmx, 32, 64));
      float cs2 = 0.0f;
#pragma unroll
      for (int m = 0; m < 4; ++m) {
        int rowb = wr * 64 + m * 16 + (lq << 2);
#pragma unroll
        for (int reg = 0; reg < 4; ++reg) {
          float v = (labR[rowb + reg] != lcn) ? acc[m][n][reg] * SCALE2 : 0.0f;
          cs2 += exp2f(v - cmx);
        }
      }
      cs2 += __shfl_xor(cs2, 16, 64);
      cs2 += __shfl_xor(cs2, 32, 64);
      if (lane < 16) { redCM[wr][wc * 64 + n * 16 + lane] = cmx; redCS[wr][wc * 64 + n * 16 + lane] = cs2; }
    }
  }

  __syncthreads();
  if (tid < 128) {
    // rows of br-block, chunk bc
    float m0 = redM[0][tid], m1 = redM[1][tid];
    float s0 = redS[0][tid], s1 = redS[1][tid];
    float M = fmaxf(m0, m1);
    float S = s0 * exp2f(m0 - M) + s1 * exp2f(m1 - M);
    pM[(size_t)bc * N_TOT + br * 128 + tid] = M;
    pS[(size_t)bc * N_TOT + br * 128 + tid] = S;
    if (br != bc) {  // rows of bc-block, chunk br (transposed tile)
      float cm0 = redCM[0][tid], cm1 = redCM[1][tid];
      float cs0 = redCS[0][tid], cs1 = redCS[1][tid];
      float CM = fmaxf(cm0, cm1);
      float CS = cs0 * exp2f(cm0 - CM) + cs1 * exp2f(cm1 - CM);
      pM[(size_t)br * N_TOT + bc * 128 + tid] = CM;
      pS[(size_t)br * N_TOT + bc * 128 + tid] = CS;
    }
  }
}

// ---------------- combine 64 chunk-partials per row, partial-sum S per block ----------------
__global__ __launch_bounds__(256) void rowred_kernel(const float* __restrict__ pM,
                                                     const float* __restrict__ pS,
                                                     float* __restrict__ blockS) {
  int row = blockIdx.x * 256 + threadIdx.x;   // 32 blocks x 256 = 8192 rows
  float M = -3.0e38f;
  for (int c = 0; c < NB; ++c) M = fmaxf(M, pM[(size_t)c * N_TOT + row]);
  float s = 0.0f;
  for (int c = 0; c < NB; ++c)
    s += pS[(size_t)c * N_TOT + row] * exp2f(pM[(size_t)c * N_TOT + row] - M);
  __shared__ float red[256];
  red[threadIdx.x] = s;
  __syncthreads();
  for (int st = 128; st > 0; st >>= 1) {
    if (threadIdx.x < st) red[threadIdx.x] += red[threadIdx.x + st];
    __syncthreads();
  }
  if (threadIdx.x == 0) blockS[blockIdx.x] = red[0];
}

// ---------------- final scalar: S, N, validity -> loss ----------------
__global__ void final_kernel(const float* __restrict__ blockS, const int* __restrict__ cnt,
                             float* __restrict__ out) {
  int lane = threadIdx.x;              // 1 wave
  float s = (lane < 32) ? blockS[lane] : 0.0f;
#pragma unroll
  for (int off = 1; off < 64; off <<= 1) s += __shfl_xor(s, off, 64);
  if (lane == 0) {
    double Stot = (double)s;
    long long sumsq = 0;
    int nval = 0;
    for (int c = 0; c < 128; ++c) {
      long long cc = cnt[c];
      sumsq += cc * cc;
      if (cc > 0 && cc < BSZ) nval += 2 * (int)cc;   // valid rows iff not all labels equal
    }
    double Nd = (double)N_TOT * (double)N_TOT - 4.0 * (double)sumsq;
    float loss;
    if (Nd <= 0.0 || nval == 0) {
      loss = logf(1e-6f);              // all_zero branch: xv stays 0 -> log(eps)
    } else {
      float x = (float)(Stot / Nd);
      loss = ((float)nval * logf(x + 1e-6f) +
              (float)(N_TOT - nval) * logf(1e-6f)) / (float)N_TOT;
    }
    out[0] = loss;
  }
}

extern "C" void kernel_launch(void* const* d_in, const int* in_sizes, int n_in,
                              void* d_out, int out_size, void* d_ws, size_t ws_size,
                              hipStream_t stream) {
  const float* feat = (const float*)d_in[0];
  const int* labels = (const int*)d_in[1];
  float* out = (float*)d_out;

  char* ws = (char*)d_ws;
  __hip_bfloat16* P  = (__hip_bfloat16*)(ws);                     // 8192*384*2 = 6,291,456
  __hip_bfloat16* Q  = (__hip_bfloat16*)(ws + 6291456);           // 6,291,456
  float* pM          = (float*)(ws + 12582912);                   // 8192*64*4 = 2,097,152
  float* pS          = (float*)(ws + 14680064);                   // 2,097,152
  int* cnt           = (int*)(ws + 16777216);                     // 512
  float* blockS      = (float*)(ws + 16777728);                   // 128

  prep_kernel<<<4097, 256, 0, stream>>>(feat, labels, P, Q, cnt);
  gemm_kernel<<<NBLK_TRI, 256, 0, stream>>>(P, Q, labels, pM, pS);
  rowred_kernel<<<32, 256, 0, stream>>>(pM, pS, blockS);
  final_kernel<<<1, 64, 0, stream>>>(blockS, cnt, out);
}

// Round 3
// 83.919 us; speedup vs baseline: 2.0820x; 1.4443x over previous
//
#include <hip/hip_runtime.h>
#include <hip/hip_bf16.h>
#include <stdint.h>

#define N_TOT 8192
#define BSZ   4096
#define NB    64
#define SCALE2 28.853900817779268f   // 20 * log2(e): base-2 domain

typedef _Float16 f16x8 __attribute__((ext_vector_type(8)));
typedef float f32x4 __attribute__((ext_vector_type(4)));

// ---------------- prep: f32 -> asymmetric fp16 split H (=fp16(x)) and L (=fp16(x-H)) ----------------
__global__ __launch_bounds__(256) void prep_kernel(
    const float* __restrict__ feat, const int* __restrict__ labels,
    _Float16* __restrict__ H, _Float16* __restrict__ L, int* __restrict__ cnt) {
  if (blockIdx.x == 512) {   // label histogram (labels in [0,100))
    __shared__ int h[128];
    if (threadIdx.x < 128) h[threadIdx.x] = 0;
    __syncthreads();
    for (int i = threadIdx.x; i < BSZ; i += 256) atomicAdd(&h[labels[i] & 127], 1);
    __syncthreads();
    if (threadIdx.x < 128) cnt[threadIdx.x] = h[threadIdx.x];
    return;
  }
  int idx = blockIdx.x * 256 + threadIdx.x;   // 131072 threads, 8 elems each
  int r = idx >> 4, c8 = (idx & 15) << 3;
  int b = r & (BSZ - 1), v = r >> 12;         // cf row r = features[b, v, :]
  const float* src = feat + ((size_t)((b << 1) + v) << 7) + c8;
  float4 x0 = *(const float4*)src;
  float4 x1 = *(const float4*)(src + 4);
  float xs[8] = {x0.x, x0.y, x0.z, x0.w, x1.x, x1.y, x1.z, x1.w};
  f16x8 hv, lv;
#pragma unroll
  for (int j = 0; j < 8; ++j) {
    _Float16 hh = (_Float16)xs[j];
    hv[j] = hh;
    lv[j] = (_Float16)(xs[j] - (float)hh);
  }
  *(f16x8*)(H + (size_t)r * 128 + c8) = hv;
  *(f16x8*)(L + (size_t)r * 128 + c8) = lv;
}

// ---------------- fused Gram GEMM + per-row online max/exp2sum, 2-phase prefetch ----------------
// C[i][j] = sum_k X[i][k]*fp16(X[j][k]):  A-panel = [H|L] (K=256), B-panel = [H|H].
// Transposed MFMA: acc[m][n] holds C[row = wr*64+m*16+(lane&15)][col = wc*64+n*16+lq*4+reg].
__global__ __launch_bounds__(256) void gemm_kernel(
    const _Float16* __restrict__ H, const _Float16* __restrict__ L,
    const int* __restrict__ labels,
    float* __restrict__ pM, float* __restrict__ pS) {
  __shared__ __align__(16) char lds[2][32768];       // [buf][A 16K | B 16K]
  __shared__ int labR[128], labC[128];
  __shared__ float redM[2][128], redS[2][128];

  // bijective XCD-aware swizzle (4096 % 8 == 0)
  int orig = blockIdx.x;
  int wg = (orig & 7) * 512 + (orig >> 3);
  int br = wg >> 6, bc = wg & 63;

  int tid = threadIdx.x, lane = tid & 63, wave = tid >> 6;
  int wr = wave >> 1, wc = wave & 1;
  int lq = lane >> 4, lr16 = lane & 15;

  if (tid < 128) {
    labR[tid] = labels[(br * 128 + tid) & (BSZ - 1)];
    labC[tid] = labels[(bc * 128 + tid) & (BSZ - 1)];
  }

  // staging addressing: lane fills 16B slot cs of row (rnd*32+wave*8+srow); logical
  // chunk cl = cs ^ (row&7) fetched so that swizzled ds_read finds it (rule #21).
  int srow = lane >> 3, cs = lane & 7;
  int cl = cs ^ srow;                               // row&7 == srow
  size_t aoffg[4], boffg[4];
#pragma unroll
  for (int rnd = 0; rnd < 4; ++rnd) {
    int row = rnd * 32 + wave * 8 + srow;
    aoffg[rnd] = (size_t)(br * 128 + row) * 128 + cl * 8;
    boffg[rnd] = (size_t)(bc * 128 + row) * 128 + cl * 8;
  }

  // fragment read offsets (fixed across kt)
  int aoffl[4], axor[4], boffl[4], bxor[4];
#pragma unroll
  for (int m = 0; m < 4; ++m) {
    int rowA = wr * 64 + m * 16 + lr16;
    aoffl[m] = rowA * 128; axor[m] = rowA & 7;
    int rowB = wc * 64 + m * 16 + lr16;
    boffl[m] = rowB * 128; bxor[m] = rowB & 7;
  }

  f32x4 acc[4][4];
#pragma unroll
  for (int m = 0; m < 4; ++m)
#pragma unroll
    for (int n = 0; n < 4; ++n) acc[m][n] = f32x4{0.f, 0.f, 0.f, 0.f};

#define STAGE(KT, B)                                                                     \
  {                                                                                      \
    const _Float16* Asrc = ((KT) < 2) ? H : L;                                           \
    int koff = ((KT) & 1) * 64;                                                          \
    _Pragma("unroll")                                                                    \
    for (int rnd = 0; rnd < 4; ++rnd) {                                                  \
      __builtin_amdgcn_global_load_lds(                                                  \
          (const __attribute__((address_space(1))) void*)(Asrc + aoffg[rnd] + koff),     \
          (__attribute__((address_space(3))) void*)(&lds[(B)][rnd * 4096 + wave * 1024]),\
          16, 0, 0);                                                                     \
      __builtin_amdgcn_global_load_lds(                                                  \
          (const __attribute__((address_space(1))) void*)(H + boffg[rnd] + koff),        \
          (__attribute__((address_space(3))) void*)(&lds[(B)][16384 + rnd * 4096 + wave * 1024]), \
          16, 0, 0);                                                                     \
    }                                                                                    \
  }

  STAGE(0, 0);                                   // prologue: tile 0 in flight (8 ops)
#pragma unroll
  for (int kt = 0; kt < 4; ++kt) {
    if (kt < 3) STAGE(kt + 1, (kt + 1) & 1);     // prefetch next tile (+8 ops)
    if (kt == 0)      asm volatile("s_waitcnt vmcnt(8) lgkmcnt(0)" ::: "memory");
    else if (kt < 3)  asm volatile("s_waitcnt vmcnt(8)" ::: "memory");   // current tile done, next stays in flight
    else              asm volatile("s_waitcnt vmcnt(0)" ::: "memory");
    __builtin_amdgcn_s_barrier();
    asm volatile("" ::: "memory");
    const char* A = (const char*)lds[kt & 1];
    const char* B = (const char*)lds[kt & 1] + 16384;
#pragma unroll
    for (int kk = 0; kk < 2; ++kk) {
      int cb = kk * 4 + lq;
      f16x8 afr[4], bfr[4];
#pragma unroll
      for (int m = 0; m < 4; ++m) afr[m] = *(const f16x8*)(A + aoffl[m] + ((cb ^ axor[m]) << 4));
#pragma unroll
      for (int n = 0; n < 4; ++n) bfr[n] = *(const f16x8*)(B + boffl[n] + ((cb ^ bxor[n]) << 4));
#pragma unroll
      for (int m = 0; m < 4; ++m)
#pragma unroll
        for (int n = 0; n < 4; ++n)   // swapped operands -> transposed C/D layout
          acc[m][n] = __builtin_amdgcn_mfma_f32_16x16x32_f16(bfr[n], afr[m], acc[m][n], 0, 0, 0);
    }
    asm volatile("" ::: "memory");
    __builtin_amdgcn_s_barrier();                // protect buf before next STAGE overwrites
    asm volatile("" ::: "memory");
  }
#undef STAGE

  // ---- epilogue: mask, per-row max & exp2-sum (row lane-resident: in-thread 16 + 2 shfl) ----
  int lcv[16];
#pragma unroll
  for (int n = 0; n < 4; ++n)
#pragma unroll
    for (int reg = 0; reg < 4; ++reg)
      lcv[n * 4 + reg] = labC[wc * 64 + n * 16 + lq * 4 + reg];

#pragma unroll
  for (int m = 0; m < 4; ++m) {
    int lr = labR[wr * 64 + m * 16 + lr16];
    float v[16];
#pragma unroll
    for (int n = 0; n < 4; ++n)
#pragma unroll
      for (int reg = 0; reg < 4; ++reg)
        v[n * 4 + reg] = (lr != lcv[n * 4 + reg]) ? acc[m][n][reg] * SCALE2 : 0.0f;
    float mx = v[0];
#pragma unroll
    for (int i = 1; i < 16; ++i) mx = fmaxf(mx, v[i]);
    mx = fmaxf(mx, __shfl_xor(mx, 16, 64));
    mx = fmaxf(mx, __shfl_xor(mx, 32, 64));
    float s = 0.0f;
#pragma unroll
    for (int i = 0; i < 16; ++i) s += exp2f(v[i] - mx);
    s += __shfl_xor(s, 16, 64);
    s += __shfl_xor(s, 32, 64);
    if (lane < 16) { redM[wc][wr * 64 + m * 16 + lane] = mx; redS[wc][wr * 64 + m * 16 + lane] = s; }
  }
  __syncthreads();
  if (tid < 128) {
    float m0 = redM[0][tid], m1 = redM[1][tid];
    float s0 = redS[0][tid], s1 = redS[1][tid];
    float M = fmaxf(m0, m1);
    float S = s0 * exp2f(m0 - M) + s1 * exp2f(m1 - M);
    pM[(size_t)bc * N_TOT + br * 128 + tid] = M;
    pS[(size_t)bc * N_TOT + br * 128 + tid] = S;
  }
}

// ---------------- combine 64 chunk-partials per row, partial-sum S per block ----------------
__global__ __launch_bounds__(256) void rowred_kernel(const float* __restrict__ pM,
                                                     const float* __restrict__ pS,
                                                     float* __restrict__ blockS) {
  int row = blockIdx.x * 256 + threadIdx.x;   // 32 blocks x 256 = 8192 rows
  float M = -3.0e38f;
  for (int c = 0; c < NB; ++c) M = fmaxf(M, pM[(size_t)c * N_TOT + row]);
  float s = 0.0f;
  for (int c = 0; c < NB; ++c)
    s += pS[(size_t)c * N_TOT + row] * exp2f(pM[(size_t)c * N_TOT + row] - M);
  __shared__ float red[256];
  red[threadIdx.x] = s;
  __syncthreads();
  for (int st = 128; st > 0; st >>= 1) {
    if (threadIdx.x < st) red[threadIdx.x] += red[threadIdx.x + st];
    __syncthreads();
  }
  if (threadIdx.x == 0) blockS[blockIdx.x] = red[0];
}

// ---------------- final scalar: S, N, validity -> loss ----------------
__global__ void final_kernel(const float* __restrict__ blockS, const int* __restrict__ cnt,
                             float* __restrict__ out) {
  int lane = threadIdx.x;              // 1 wave
  float s = (lane < 32) ? blockS[lane] : 0.0f;
#pragma unroll
  for (int off = 1; off < 64; off <<= 1) s += __shfl_xor(s, off, 64);
  if (lane == 0) {
    double Stot = (double)s;
    long long sumsq = 0;
    int nval = 0;
    for (int c = 0; c < 128; ++c) {
      long long cc = cnt[c];
      sumsq += cc * cc;
      if (cc > 0 && cc < BSZ) nval += 2 * (int)cc;   // valid rows iff not all labels equal
    }
    double Nd = (double)N_TOT * (double)N_TOT - 4.0 * (double)sumsq;
    float loss;
    if (Nd <= 0.0 || nval == 0) {
      loss = logf(1e-6f);              // all_zero branch: xv stays 0 -> log(eps)
    } else {
      float x = (float)(Stot / Nd);
      loss = ((float)nval * logf(x + 1e-6f) +
              (float)(N_TOT - nval) * logf(1e-6f)) / (float)N_TOT;
    }
    out[0] = loss;
  }
}

extern "C" void kernel_launch(void* const* d_in, const int* in_sizes, int n_in,
                              void* d_out, int out_size, void* d_ws, size_t ws_size,
                              hipStream_t stream) {
  const float* feat = (const float*)d_in[0];
  const int* labels = (const int*)d_in[1];
  float* out = (float*)d_out;

  char* ws = (char*)d_ws;
  _Float16* H   = (_Float16*)(ws);                   // 8192*128*2 = 2,097,152
  _Float16* L   = (_Float16*)(ws + 2097152);         // 2,097,152
  float* pM     = (float*)(ws + 4194304);            // 8192*64*4 = 2,097,152
  float* pS     = (float*)(ws + 6291456);            // 2,097,152
  int* cnt      = (int*)(ws + 8388608);              // 512
  float* blockS = (float*)(ws + 8389120);            // 128

  prep_kernel<<<513, 256, 0, stream>>>(feat, labels, H, L, cnt);
  gemm_kernel<<<4096, 256, 0, stream>>>(H, L, labels, pM, pS);
  rowred_kernel<<<32, 256, 0, stream>>>(pM, pS, blockS);
  final_kernel<<<1, 64, 0, stream>>>(blockS, cnt, out);
}

// Round 5
// 72.644 us; speedup vs baseline: 2.4051x; 1.1552x over previous
//
#include <hip/hip_runtime.h>
#include <hip/hip_bf16.h>
#include <stdint.h>

#define N_TOT 8192
#define BSZ   4096
#define NCH   32                     // 8192/256 column chunks
#define SCALE2 28.853900817779268f   // 20 * log2(e): base-2 domain

typedef _Float16 f16x8 __attribute__((ext_vector_type(8)));
typedef float f32x4 __attribute__((ext_vector_type(4)));

// ---------------- prep: f32 -> asymmetric fp16 split H (=fp16(x)) and L (=fp16(x-H)) ----------------
__global__ __launch_bounds__(256) void prep_kernel(
    const float* __restrict__ feat, const int* __restrict__ labels,
    _Float16* __restrict__ H, _Float16* __restrict__ L, int* __restrict__ cnt) {
  if (blockIdx.x == 512) {   // label histogram (labels in [0,100))
    __shared__ int h[128];
    if (threadIdx.x < 128) h[threadIdx.x] = 0;
    __syncthreads();
    for (int i = threadIdx.x; i < BSZ; i += 256) atomicAdd(&h[labels[i] & 127], 1);
    __syncthreads();
    if (threadIdx.x < 128) cnt[threadIdx.x] = h[threadIdx.x];
    return;
  }
  int idx = blockIdx.x * 256 + threadIdx.x;   // 131072 threads, 8 elems each
  int r = idx >> 4, c8 = (idx & 15) << 3;
  int b = r & (BSZ - 1), v = r >> 12;         // cf row r = features[b, v, :]
  const float* src = feat + ((size_t)((b << 1) + v) << 7) + c8;
  float4 x0 = *(const float4*)src;
  float4 x1 = *(const float4*)(src + 4);
  float xs[8] = {x0.x, x0.y, x0.z, x0.w, x1.x, x1.y, x1.z, x1.w};
  f16x8 hv, lv;
#pragma unroll
  for (int j = 0; j < 8; ++j) {
    _Float16 hh = (_Float16)xs[j];
    hv[j] = hh;
    lv[j] = (_Float16)(xs[j] - (float)hh);
  }
  *(f16x8*)(H + (size_t)r * 128 + c8) = hv;
  *(f16x8*)(L + (size_t)r * 128 + c8) = lv;
}

// ---------------- fused Gram GEMM, 256x256 tile, 8 waves, 4-phase K-steps ----------------
// C[i][j] = sum_k X[i][k]*fp16(X[j][k]):  A-panel = [H|L] (K=256), B-panel = [H|H].
// Transposed MFMA: acc[m][n] holds C[row = wr*128+m*16+(lane&15)][col = wc*64+n*16+lq*4+reg].
// Static LDS kept at exactly 128 KiB (m201-verified size): labels read direct from
// global in the epilogue; combine arrays alias the (then-dead) staging buffer.
__global__ __launch_bounds__(512, 2) void gemm_kernel(
    const _Float16* __restrict__ H, const _Float16* __restrict__ L,
    const int* __restrict__ labels,
    float* __restrict__ pM, float* __restrict__ pS) {
  __shared__ __align__(16) char lds[2][65536];       // [buf][A 32K | B 32K] = 128 KiB total

  // bijective XCD-aware swizzle (1024 % 8 == 0)
  int orig = blockIdx.x;
  int wg = (orig & 7) * 128 + (orig >> 3);
  int br = wg >> 5, bc = wg & 31;

  int tid = threadIdx.x, lane = tid & 63, wave = tid >> 6;
  int wr = wave >> 2, wc = wave & 3;
  int lq = lane >> 4, lr16 = lane & 15;

  // staging addressing (rule #21): lane fills 16B slot cs of its row; logical chunk
  // cl = cs ^ (row&7) fetched so the swizzled ds_read finds it. LDS dest linear.
  int srow = tid >> 3;          // 0..63: row within 64-row group
  int cs = tid & 7;
  int cl = cs ^ (srow & 7);
  size_t aoffg[4], boffg[4];
#pragma unroll
  for (int rnd = 0; rnd < 4; ++rnd) {
    int row = rnd * 64 + srow;
    aoffg[rnd] = (size_t)(br * 256 + row) * 128 + cl * 8;
    boffg[rnd] = (size_t)(bc * 256 + row) * 128 + cl * 8;
  }

  // fragment LDS offsets (byte) and row-xor for swizzled reads
  int aoffl[2][4], axor[2][4], boffl[4], bxor[4];
#pragma unroll
  for (int mh = 0; mh < 2; ++mh)
#pragma unroll
    for (int mi = 0; mi < 4; ++mi) {
      int rowA = wr * 128 + mh * 64 + mi * 16 + lr16;
      aoffl[mh][mi] = rowA * 128; axor[mh][mi] = rowA & 7;
    }
#pragma unroll
  for (int ni = 0; ni < 4; ++ni) {
    int rowB = wc * 64 + ni * 16 + lr16;
    boffl[ni] = rowB * 128; bxor[ni] = rowB & 7;
  }

  f32x4 acc[8][4];
#pragma unroll
  for (int m = 0; m < 8; ++m)
#pragma unroll
    for (int n = 0; n < 4; ++n) acc[m][n] = f32x4{0.f, 0.f, 0.f, 0.f};

#define STAGE(T)                                                                          \
  {                                                                                       \
    const _Float16* Asrc = ((T) < 2) ? H : L;                                             \
    const int koff = ((T) & 1) * 64;                                                      \
    const int bb = (T) & 1;                                                               \
    _Pragma("unroll")                                                                     \
    for (int rnd = 0; rnd < 4; ++rnd) {                                                   \
      __builtin_amdgcn_global_load_lds(                                                   \
          (const __attribute__((address_space(1))) void*)(Asrc + aoffg[rnd] + koff),      \
          (__attribute__((address_space(3))) void*)(&lds[bb][rnd * 8192 + wave * 1024]),  \
          16, 0, 0);                                                                      \
      __builtin_amdgcn_global_load_lds(                                                   \
          (const __attribute__((address_space(1))) void*)(H + boffg[rnd] + koff),         \
          (__attribute__((address_space(3))) void*)(&lds[bb][32768 + rnd * 8192 + wave * 1024]), \
          16, 0, 0);                                                                      \
    }                                                                                     \
  }

#define LGKM(N)                                                          \
  asm volatile("s_waitcnt lgkmcnt(" #N ")" ::: "memory");                \
  __builtin_amdgcn_sched_barrier(0);

#define READA(DST, MH, KK)                                               \
  _Pragma("unroll")                                                      \
  for (int mi = 0; mi < 4; ++mi)                                         \
    DST[mi] = *(const f16x8*)(Ab + aoffl[MH][mi] + ((((KK) * 4 + lq) ^ axor[MH][mi]) << 4));

#define READB(DST, KK)                                                   \
  _Pragma("unroll")                                                      \
  for (int ni = 0; ni < 4; ++ni)                                         \
    DST[ni] = *(const f16x8*)(Bb + boffl[ni] + ((((KK) * 4 + lq) ^ bxor[ni]) << 4));

#define MFMAS(MH, AF, BF)                                                \
  __builtin_amdgcn_s_setprio(1);                                         \
  _Pragma("unroll")                                                      \
  for (int mi = 0; mi < 4; ++mi)                                         \
    _Pragma("unroll")                                                    \
    for (int ni = 0; ni < 4; ++ni)                                       \
      acc[(MH) * 4 + mi][ni] = __builtin_amdgcn_mfma_f32_16x16x32_f16(   \
          BF[ni], AF[mi], acc[(MH) * 4 + mi][ni], 0, 0, 0);              \
  __builtin_amdgcn_s_setprio(0);

  STAGE(0);                                    // tile 0 in flight (8 loads)
#pragma unroll
  for (int t = 0; t < 4; ++t) {
    if (t < 3) STAGE(t + 1);                   // prefetch next K-step into other buf
    if (t < 3) { asm volatile("s_waitcnt vmcnt(8)" ::: "memory"); }      // this step done, next in flight
    else       { asm volatile("s_waitcnt vmcnt(0)" ::: "memory"); }
    __builtin_amdgcn_sched_barrier(0);
    __builtin_amdgcn_s_barrier();
    asm volatile("" ::: "memory");
    const char* Ab = (const char*)lds[t & 1];
    const char* Bb = Ab + 32768;
    f16x8 Afr[2][4], Bfr[2][4];
    READA(Afr[0], 0, 0); READB(Bfr[0], 0);     // phase-0 frags
    // phase 0: prefetch phase-1 A frags, compute (mh0,kk0)
    READA(Afr[1], 1, 0);
    LGKM(4); MFMAS(0, Afr[0], Bfr[0]);
    // phase 1: prefetch phase-2 frags (A mh0/kk1 + B kk1), compute (mh1,kk0)
    READA(Afr[0], 0, 1); READB(Bfr[1], 1);
    LGKM(8); MFMAS(1, Afr[1], Bfr[0]);
    // phase 2: prefetch phase-3 A frags, compute (mh0,kk1)
    READA(Afr[1], 1, 1);
    LGKM(4); MFMAS(0, Afr[0], Bfr[1]);
    // phase 3: compute (mh1,kk1)
    LGKM(0); MFMAS(1, Afr[1], Bfr[1]);
    asm volatile("" ::: "memory");
    __builtin_amdgcn_s_barrier();              // buf free for next STAGE / LDS reuse
    asm volatile("" ::: "memory");
  }
#undef STAGE
#undef LGKM
#undef READA
#undef READB
#undef MFMAS

  // ---- epilogue: mask, per-row max & exp2-sum (rows lane-resident: in-thread 16 + 2 shfl) ----
  // Staging LDS is dead now (final barrier drained all reads) -> alias combine arrays onto it.
  float* redM = (float*)lds;          // [4][256]
  float* redS = redM + 1024;          // [4][256]

  int lcv[16];
#pragma unroll
  for (int n = 0; n < 4; ++n)
#pragma unroll
    for (int reg = 0; reg < 4; ++reg)
      lcv[n * 4 + reg] = labels[(bc * 256 + wc * 64 + n * 16 + lq * 4 + reg) & (BSZ - 1)];

#pragma unroll
  for (int m = 0; m < 8; ++m) {
    int lr = labels[(br * 256 + wr * 128 + m * 16 + lr16) & (BSZ - 1)];
    float v[16];
#pragma unroll
    for (int n = 0; n < 4; ++n)
#pragma unroll
      for (int reg = 0; reg < 4; ++reg)
        v[n * 4 + reg] = (lr != lcv[n * 4 + reg]) ? acc[m][n][reg] * SCALE2 : 0.0f;
    // tree max
    float m01 = fmaxf(v[0], v[1]),  m23 = fmaxf(v[2], v[3]);
    float m45 = fmaxf(v[4], v[5]),  m67 = fmaxf(v[6], v[7]);
    float m89 = fmaxf(v[8], v[9]),  mab = fmaxf(v[10], v[11]);
    float mcd = fmaxf(v[12], v[13]), mef = fmaxf(v[14], v[15]);
    float mx = fmaxf(fmaxf(fmaxf(m01, m23), fmaxf(m45, m67)),
                     fmaxf(fmaxf(m89, mab), fmaxf(mcd, mef)));
    mx = fmaxf(mx, __shfl_xor(mx, 16, 64));
    mx = fmaxf(mx, __shfl_xor(mx, 32, 64));
    // tree sum of exp2
    float s0 = 0.f, s1 = 0.f, s2 = 0.f, s3 = 0.f;
#pragma unroll
    for (int i = 0; i < 4; ++i) {
      s0 += exp2f(v[i] - mx);
      s1 += exp2f(v[4 + i] - mx);
      s2 += exp2f(v[8 + i] - mx);
      s3 += exp2f(v[12 + i] - mx);
    }
    float s = (s0 + s1) + (s2 + s3);
    s += __shfl_xor(s, 16, 64);
    s += __shfl_xor(s, 32, 64);
    if (lane < 16) {
      redM[wc * 256 + wr * 128 + m * 16 + lane] = mx;
      redS[wc * 256 + wr * 128 + m * 16 + lane] = s;
    }
  }
  __syncthreads();
  if (tid < 256) {
    float m0 = redM[tid], m1 = redM[256 + tid], m2 = redM[512 + tid], m3 = redM[768 + tid];
    float M = fmaxf(fmaxf(m0, m1), fmaxf(m2, m3));
    float S = redS[tid] * exp2f(m0 - M) + redS[256 + tid] * exp2f(m1 - M) +
              redS[512 + tid] * exp2f(m2 - M) + redS[768 + tid] * exp2f(m3 - M);
    pM[(size_t)bc * N_TOT + br * 256 + tid] = M;
    pS[(size_t)bc * N_TOT + br * 256 + tid] = S;
  }
}

// ---------------- combine 32 chunk-partials per row, partial-sum S per block ----------------
__global__ __launch_bounds__(256) void rowred_kernel(const float* __restrict__ pM,
                                                     const float* __restrict__ pS,
                                                     float* __restrict__ blockS) {
  int row = blockIdx.x * 256 + threadIdx.x;   // 32 blocks x 256 = 8192 rows
  float M = -3.0e38f;
  for (int c = 0; c < NCH; ++c) M = fmaxf(M, pM[(size_t)c * N_TOT + row]);
  float s = 0.0f;
  for (int c = 0; c < NCH; ++c)
    s += pS[(size_t)c * N_TOT + row] * exp2f(pM[(size_t)c * N_TOT + row] - M);
  __shared__ float red[256];
  red[threadIdx.x] = s;
  __syncthreads();
  for (int st = 128; st > 0; st >>= 1) {
    if (threadIdx.x < st) red[threadIdx.x] += red[threadIdx.x + st];
    __syncthreads();
  }
  if (threadIdx.x == 0) blockS[blockIdx.x] = red[0];
}

// ---------------- final scalar: S, N, validity -> loss ----------------
__global__ void final_kernel(const float* __restrict__ blockS, const int* __restrict__ cnt,
                             float* __restrict__ out) {
  int lane = threadIdx.x;              // 1 wave
  float s = (lane < 32) ? blockS[lane] : 0.0f;
#pragma unroll
  for (int off = 1; off < 64; off <<= 1) s += __shfl_xor(s, off, 64);
  if (lane == 0) {
    double Stot = (double)s;
    long long sumsq = 0;
    int nval = 0;
    for (int c = 0; c < 128; ++c) {
      long long cc = cnt[c];
      sumsq += cc * cc;
      if (cc > 0 && cc < BSZ) nval += 2 * (int)cc;   // valid rows iff not all labels equal
    }
    double Nd = (double)N_TOT * (double)N_TOT - 4.0 * (double)sumsq;
    float loss;
    if (Nd <= 0.0 || nval == 0) {
      loss = logf(1e-6f);              // all_zero branch: xv stays 0 -> log(eps)
    } else {
      float x = (float)(Stot / Nd);
      loss = ((float)nval * logf(x + 1e-6f) +
              (float)(N_TOT - nval) * logf(1e-6f)) / (float)N_TOT;
    }
    out[0] = loss;
  }
}

extern "C" void kernel_launch(void* const* d_in, const int* in_sizes, int n_in,
                              void* d_out, int out_size, void* d_ws, size_t ws_size,
                              hipStream_t stream) {
  const float* feat = (const float*)d_in[0];
  const int* labels = (const int*)d_in[1];
  float* out = (float*)d_out;

  char* ws = (char*)d_ws;
  _Float16* H   = (_Float16*)(ws);                   // 8192*128*2 = 2,097,152
  _Float16* L   = (_Float16*)(ws + 2097152);         // 2,097,152
  float* pM     = (float*)(ws + 4194304);            // 32*8192*4 = 1,048,576
  float* pS     = (float*)(ws + 5242880);            // 1,048,576
  int* cnt      = (int*)(ws + 6291456);              // 512
  float* blockS = (float*)(ws + 6291968);            // 128

  prep_kernel<<<513, 256, 0, stream>>>(feat, labels, H, L, cnt);
  gemm_kernel<<<1024, 512, 0, stream>>>(H, L, labels, pM, pS);
  rowred_kernel<<<32, 256, 0, stream>>>(pM, pS, blockS);
  final_kernel<<<1, 64, 0, stream>>>(blockS, cnt, out);
}

// Round 6
// 58.326 us; speedup vs baseline: 2.9956x; 1.2455x over previous
//
#include <hip/hip_runtime.h>
#include <hip/hip_bf16.h>
#include <stdint.h>

#define N_TOT 8192
#define BSZ   4096
#define NCH   4                      // 8192/2048 column groups
#define SCALE2 28.853900817779268f   // 20 * log2(e): base-2 domain

typedef _Float16 f16x8 __attribute__((ext_vector_type(8)));
typedef float f32x4 __attribute__((ext_vector_type(4)));

// ---------------- prep: f32 -> fp16 H; block 512 = label hist + byte labels ----------------
__global__ __launch_bounds__(256) void prep_kernel(
    const float* __restrict__ feat, const int* __restrict__ labels,
    _Float16* __restrict__ H, unsigned char* __restrict__ lab8, int* __restrict__ cnt) {
  if (blockIdx.x == 512) {
    __shared__ int h[128];
    if (threadIdx.x < 128) h[threadIdx.x] = 0;
    __syncthreads();
    for (int i = threadIdx.x; i < BSZ; i += 256) atomicAdd(&h[labels[i] & 127], 1);
    __syncthreads();
    if (threadIdx.x < 128) cnt[threadIdx.x] = h[threadIdx.x];
    for (int i = threadIdx.x; i < N_TOT; i += 256)
      lab8[i] = (unsigned char)labels[i & (BSZ - 1)];
    return;
  }
  int idx = blockIdx.x * 256 + threadIdx.x;   // 131072 threads, 8 halves each
  int r = idx >> 4, c8 = (idx & 15) << 3;
  int b = r & (BSZ - 1), v = r >> 12;         // cf row r = features[b, v, :]
  const float* src = feat + ((size_t)((b << 1) + v) << 7) + c8;
  float4 x0 = *(const float4*)src;
  float4 x1 = *(const float4*)(src + 4);
  float xs[8] = {x0.x, x0.y, x0.z, x0.w, x1.x, x1.y, x1.z, x1.w};
  f16x8 hv;
#pragma unroll
  for (int j = 0; j < 8; ++j) hv[j] = (_Float16)xs[j];
  *(f16x8*)(H + (size_t)r * 128 + c8) = hv;
}

// ---------------- strip GEMM: 64 rows x 2048 cols per block, K=128, A in registers ----------------
// Block = (strip, cg). 4 waves in 2x2: wr row-half (32 rows), wc col-half (64 of 128 per iter).
// acc[m][n][reg] = C[row = strip*64 + wr*32 + m*16 + lr16][col = cg*2048 + it*128 + wc*64 + n*16 + lq*4 + reg]
// A pre-scaled by SCALE2 in-register; online (max, exp2-sum) per row across 16 col-iters.
__global__ __launch_bounds__(256, 2) void gemm_kernel(
    const _Float16* __restrict__ H, const int* __restrict__ labels,
    const unsigned char* __restrict__ lab8,
    float* __restrict__ pM, float* __restrict__ pS) {
  __shared__ __align__(16) char ldsA[16384];        // A [64 rows][128 K] fp16
  __shared__ __align__(16) char ldsB[2][16384];     // B halves [128 cols][64 K] fp16, dbuf
  __shared__ __align__(16) unsigned char ldsLab[2048];  // cg's 2048 col labels

  // XCD swizzle: cg = xcd>>1 (2 XCDs per col-group share B panels in L2); bijective.
  int orig = blockIdx.x;                 // 512
  int xcd = orig & 7, idx = orig >> 3;   // idx in [0,64)
  int strip = (xcd & 1) * 64 + idx;      // [0,128)
  int cg = xcd >> 1;                     // [0,4)

  int tid = threadIdx.x, lane = tid & 63, wave = tid >> 6;
  int wr = wave >> 1, wc = wave & 1;
  int lq = lane >> 4, lr16 = lane & 15;

  // row labels (issued first; covered by first counted vmcnt)
  int lrw[2];
#pragma unroll
  for (int m = 0; m < 2; ++m)
    lrw[m] = labels[(strip * 64 + wr * 32 + m * 16 + lr16) & (BSZ - 1)];

  // ---- staging source addresses (rule #21: linear LDS dest, inverse-XOR-swizzled source) ----
  // A: dest off = rnd*4096 + wave*1024 + lane*16 -> row = rnd*16+wave*4+(lane>>4), slot = lane&15
  // B: dest off = rnd*4096 + wave*1024 + lane*16 -> row = rnd*32+wave*8+(lane>>3), slot = lane&7
  uint32_t bgoff[4];
#pragma unroll
  for (int rnd = 0; rnd < 4; ++rnd) {
    int brow = rnd * 32 + wave * 8 + (lane >> 3);
    int cl = (lane & 7) ^ (brow & 7);
    bgoff[rnd] = (uint32_t)(cg * 2048 + brow) * 128 + cl * 8;
  }

  // prologue stages: A (4 ops) + labels (1 op, waves 0-1) + B(it0,kh0)->buf0 (4 ops)
#pragma unroll
  for (int rnd = 0; rnd < 4; ++rnd) {
    int arow = rnd * 16 + wave * 4 + (lane >> 4);
    int cl = (lane & 15) ^ (arow & 7);
    __builtin_amdgcn_global_load_lds(
        (const __attribute__((address_space(1))) void*)(H + (uint32_t)(strip * 64 + arow) * 128 + cl * 8),
        (__attribute__((address_space(3))) void*)(&ldsA[rnd * 4096 + wave * 1024]), 16, 0, 0);
  }
  if (tid < 128)
    __builtin_amdgcn_global_load_lds(
        (const __attribute__((address_space(1))) void*)(lab8 + cg * 2048 + tid * 16),
        (__attribute__((address_space(3))) void*)(&ldsLab[wave * 1024]), 16, 0, 0);

#define STAGE_B(IT, KH, BUF)                                                              \
  {                                                                                       \
    _Pragma("unroll")                                                                     \
    for (int rnd = 0; rnd < 4; ++rnd)                                                     \
      __builtin_amdgcn_global_load_lds(                                                   \
          (const __attribute__((address_space(1))) void*)(H + bgoff[rnd] + (uint32_t)(IT) * 16384 + (KH) * 64), \
          (__attribute__((address_space(3))) void*)(&ldsB[BUF][rnd * 4096 + wave * 1024]), 16, 0, 0); \
  }

  STAGE_B(0, 0, 0);

  // fragment read offsets
  int broff[4], bxr[4];
#pragma unroll
  for (int ni = 0; ni < 4; ++ni) {
    int brow = wc * 64 + ni * 16 + lr16;
    broff[ni] = brow * 128; bxr[ni] = brow & 7;
  }
  int aoff[2], axr[2];
#pragma unroll
  for (int m = 0; m < 2; ++m) {
    int arow = wr * 32 + m * 16 + lr16;
    aoff[m] = arow * 256; axr[m] = arow & 7;
  }

  f16x8 Areg[2][4];
  f32x4 acc[2][4];
  float mxv[2] = {-3.0e38f, -3.0e38f}, sv[2] = {0.0f, 0.0f};

#define READB(BUF)                                                                        \
  _Pragma("unroll")                                                                       \
  for (int kk = 0; kk < 2; ++kk)                                                          \
    _Pragma("unroll")                                                                     \
    for (int ni = 0; ni < 4; ++ni)                                                        \
      Bf[kk][ni] = *(const f16x8*)(&ldsB[BUF][broff[ni] + (((kk * 4 + lq) ^ bxr[ni]) << 4)]);

#define MFMAS(KB)                                                                         \
  __builtin_amdgcn_s_setprio(1);                                                          \
  _Pragma("unroll")                                                                       \
  for (int kk = 0; kk < 2; ++kk)                                                          \
    _Pragma("unroll")                                                                     \
    for (int m = 0; m < 2; ++m)                                                           \
      _Pragma("unroll")                                                                   \
      for (int ni = 0; ni < 4; ++ni)                                                      \
        acc[m][ni] = __builtin_amdgcn_mfma_f32_16x16x32_f16(Bf[kk][ni], Areg[m][(KB) + kk], acc[m][ni], 0, 0, 0); \
  __builtin_amdgcn_s_setprio(0);

#pragma unroll 1
  for (int it = 0; it < 16; ++it) {
    // ======== kh = 0 : reads buf0, stages (it, kh1) -> buf1 ========
    STAGE_B(it, 1, 1);
    asm volatile("s_waitcnt vmcnt(4)" ::: "memory");
    __builtin_amdgcn_sched_barrier(0);
    __builtin_amdgcn_s_barrier();
    asm volatile("" ::: "memory");
    if (it == 0) {   // A staged in prologue; load frags once, pre-scale by SCALE2
#pragma unroll
      for (int m = 0; m < 2; ++m)
#pragma unroll
        for (int c = 0; c < 4; ++c) {
          f16x8 a = *(const f16x8*)(&ldsA[aoff[m] + (((c * 4 + lq) ^ axr[m]) << 4)]);
          Areg[m][c] = a * (_Float16)SCALE2;
        }
    }
#pragma unroll
    for (int m = 0; m < 2; ++m)
#pragma unroll
      for (int ni = 0; ni < 4; ++ni) acc[m][ni] = f32x4{0.f, 0.f, 0.f, 0.f};
    {
      f16x8 Bf[2][4];
      READB(0);
      MFMAS(0);
    }
    asm volatile("" ::: "memory");
    __builtin_amdgcn_s_barrier();
    asm volatile("" ::: "memory");

    // ======== kh = 1 : reads buf1, stages (it+1, kh0) -> buf0 ========
    if (it < 15) {
      STAGE_B(it + 1, 0, 0);
      asm volatile("s_waitcnt vmcnt(4)" ::: "memory");
    } else {
      asm volatile("s_waitcnt vmcnt(0)" ::: "memory");
    }
    __builtin_amdgcn_sched_barrier(0);
    __builtin_amdgcn_s_barrier();
    asm volatile("" ::: "memory");
    {
      f16x8 Bf[2][4];
      READB(1);
      MFMAS(2);
    }
    // ---- online epilogue for this 128-col tile ----
    {
      uint32_t labw[4];
#pragma unroll
      for (int ni = 0; ni < 4; ++ni)
        labw[ni] = *(const uint32_t*)(&ldsLab[it * 128 + wc * 64 + ni * 16 + lq * 4]);
#pragma unroll
      for (int m = 0; m < 2; ++m) {
        float v[16];
#pragma unroll
        for (int ni = 0; ni < 4; ++ni)
#pragma unroll
          for (int reg = 0; reg < 4; ++reg) {
            int lc = (labw[ni] >> (8 * reg)) & 255;
            v[ni * 4 + reg] = (lrw[m] != lc) ? acc[m][ni][reg] : 0.0f;
          }
        float m01 = fmaxf(v[0], v[1]),  m23 = fmaxf(v[2], v[3]);
        float m45 = fmaxf(v[4], v[5]),  m67 = fmaxf(v[6], v[7]);
        float m89 = fmaxf(v[8], v[9]),  mab = fmaxf(v[10], v[11]);
        float mcd = fmaxf(v[12], v[13]), mef = fmaxf(v[14], v[15]);
        float bm = fmaxf(fmaxf(fmaxf(m01, m23), fmaxf(m45, m67)),
                         fmaxf(fmaxf(m89, mab), fmaxf(mcd, mef)));
        float nm = fmaxf(mxv[m], bm);
        float s0 = 0.f, s1 = 0.f;
#pragma unroll
        for (int i = 0; i < 8; ++i) {
          s0 += exp2f(v[i] - nm);
          s1 += exp2f(v[8 + i] - nm);
        }
        sv[m] = sv[m] * exp2f(mxv[m] - nm) + (s0 + s1);
        mxv[m] = nm;
      }
    }
    asm volatile("" ::: "memory");
    __builtin_amdgcn_s_barrier();
    asm volatile("" ::: "memory");
  }
#undef STAGE_B
#undef READB
#undef MFMAS

  // ---- final reduce: combine lq slices (shfl) then wc halves (LDS, aliased on dead ldsA) ----
  float* redM = (float*)ldsA;          // [2][64]
  float* redS = redM + 128;
#pragma unroll
  for (int m = 0; m < 2; ++m) {
    float M = mxv[m], S = sv[m];
#pragma unroll
    for (int off = 16; off < 64; off <<= 1) {
      float Mo = __shfl_xor(M, off, 64);
      float So = __shfl_xor(S, off, 64);
      float Mn = fmaxf(M, Mo);
      S = S * exp2f(M - Mn) + So * exp2f(Mo - Mn);
      M = Mn;
    }
    if (lq == 0) {
      redM[wc * 64 + wr * 32 + m * 16 + lr16] = M;
      redS[wc * 64 + wr * 32 + m * 16 + lr16] = S;
    }
  }
  __syncthreads();
  if (tid < 64) {
    float m0 = redM[tid], m1 = redM[64 + tid];
    float M = fmaxf(m0, m1);
    float S = redS[tid] * exp2f(m0 - M) + redS[64 + tid] * exp2f(m1 - M);
    pM[(size_t)cg * N_TOT + strip * 64 + tid] = M;
    pS[(size_t)cg * N_TOT + strip * 64 + tid] = S;
  }
}

// ---------------- combine 4 chunk-partials per row, partial-sum S per block ----------------
__global__ __launch_bounds__(256) void rowred_kernel(const float* __restrict__ pM,
                                                     const float* __restrict__ pS,
                                                     float* __restrict__ blockS) {
  int row = blockIdx.x * 256 + threadIdx.x;   // 32 blocks x 256 = 8192 rows
  float M = -3.0e38f;
#pragma unroll
  for (int c = 0; c < NCH; ++c) M = fmaxf(M, pM[(size_t)c * N_TOT + row]);
  float s = 0.0f;
#pragma unroll
  for (int c = 0; c < NCH; ++c)
    s += pS[(size_t)c * N_TOT + row] * exp2f(pM[(size_t)c * N_TOT + row] - M);
  __shared__ float red[256];
  red[threadIdx.x] = s;
  __syncthreads();
  for (int st = 128; st > 0; st >>= 1) {
    if (threadIdx.x < st) red[threadIdx.x] += red[threadIdx.x + st];
    __syncthreads();
  }
  if (threadIdx.x == 0) blockS[blockIdx.x] = red[0];
}

// ---------------- final scalar: S, N, validity -> loss ----------------
__global__ void final_kernel(const float* __restrict__ blockS, const int* __restrict__ cnt,
                             float* __restrict__ out) {
  int lane = threadIdx.x;              // 1 wave
  float s = (lane < 32) ? blockS[lane] : 0.0f;
#pragma unroll
  for (int off = 1; off < 64; off <<= 1) s += __shfl_xor(s, off, 64);
  if (lane == 0) {
    double Stot = (double)s;
    long long sumsq = 0;
    int nval = 0;
    for (int c = 0; c < 128; ++c) {
      long long cc = cnt[c];
      sumsq += cc * cc;
      if (cc > 0 && cc < BSZ) nval += 2 * (int)cc;   // valid rows iff not all labels equal
    }
    double Nd = (double)N_TOT * (double)N_TOT - 4.0 * (double)sumsq;
    float loss;
    if (Nd <= 0.0 || nval == 0) {
      loss = logf(1e-6f);              // all_zero branch: xv stays 0 -> log(eps)
    } else {
      float x = (float)(Stot / Nd);
      loss = ((float)nval * logf(x + 1e-6f) +
              (float)(N_TOT - nval) * logf(1e-6f)) / (float)N_TOT;
    }
    out[0] = loss;
  }
}

extern "C" void kernel_launch(void* const* d_in, const int* in_sizes, int n_in,
                              void* d_out, int out_size, void* d_ws, size_t ws_size,
                              hipStream_t stream) {
  const float* feat = (const float*)d_in[0];
  const int* labels = (const int*)d_in[1];
  float* out = (float*)d_out;

  char* ws = (char*)d_ws;
  _Float16* H        = (_Float16*)(ws);                  // 8192*128*2 = 2,097,152
  unsigned char* lab8 = (unsigned char*)(ws + 2097152);  // 8,192
  float* pM          = (float*)(ws + 2105344);           // 4*8192*4 = 131,072
  float* pS          = (float*)(ws + 2236416);           // 131,072
  int* cnt           = (int*)(ws + 2367488);             // 512
  float* blockS      = (float*)(ws + 2368000);           // 128

  prep_kernel<<<513, 256, 0, stream>>>(feat, labels, H, lab8, cnt);
  gemm_kernel<<<512, 256, 0, stream>>>(H, labels, lab8, pM, pS);
  rowred_kernel<<<32, 256, 0, stream>>>(pM, pS, blockS);
  final_kernel<<<1, 64, 0, stream>>>(blockS, cnt, out);
}

// Round 7
// 56.509 us; speedup vs baseline: 3.0919x; 1.0322x over previous
//
#include <hip/hip_runtime.h>
#include <hip/hip_bf16.h>
#include <stdint.h>

#define N_TOT 8192
#define BSZ   4096
#define NCH   8                      // 8192/1024 column groups
#define SCALE2 28.853900817779268f   // 20 * log2(e): base-2 domain
#define SKIP_THR 125.0f              // exp2 window: terms below max-125 are f32 zeros

typedef _Float16 f16x8 __attribute__((ext_vector_type(8)));
typedef float f32x4 __attribute__((ext_vector_type(4)));

// ---------------- prep: f32 -> fp16 H; block 512 = label hist + byte labels ----------------
__global__ __launch_bounds__(256) void prep_kernel(
    const float* __restrict__ feat, const int* __restrict__ labels,
    _Float16* __restrict__ H, unsigned char* __restrict__ lab8, int* __restrict__ cnt) {
  if (blockIdx.x == 512) {
    __shared__ int h[128];
    if (threadIdx.x < 128) h[threadIdx.x] = 0;
    __syncthreads();
    for (int i = threadIdx.x; i < BSZ; i += 256) atomicAdd(&h[labels[i] & 127], 1);
    __syncthreads();
    if (threadIdx.x < 128) cnt[threadIdx.x] = h[threadIdx.x];
    for (int i = threadIdx.x; i < N_TOT; i += 256)
      lab8[i] = (unsigned char)labels[i & (BSZ - 1)];
    return;
  }
  int idx = blockIdx.x * 256 + threadIdx.x;   // 131072 threads, 8 halves each
  int r = idx >> 4, c8 = (idx & 15) << 3;
  int b = r & (BSZ - 1), v = r >> 12;         // cf row r = features[b, v, :]
  const float* src = feat + ((size_t)((b << 1) + v) << 7) + c8;
  float4 x0 = *(const float4*)src;
  float4 x1 = *(const float4*)(src + 4);
  float xs[8] = {x0.x, x0.y, x0.z, x0.w, x1.x, x1.y, x1.z, x1.w};
  f16x8 hv;
#pragma unroll
  for (int j = 0; j < 8; ++j) hv[j] = (_Float16)xs[j];
  *(f16x8*)(H + (size_t)r * 128 + c8) = hv;
}

// ---------------- strip GEMM: 64 rows x 1024 cols per block, K=128, A in registers ----------------
// Block = (strip, cg). 4 waves 2x2: wr row-half (32 rows), wc col-half (64 of 128 per iter).
// acc[m][n][reg] = C[row = strip*64+wr*32+m*16+lr16][col = cg*1024 + it*128 + wc*64+n*16+lq*4+reg]
// A pre-scaled by SCALE2; online (max, exp2-sum) per row with wave-uniform exp-skip.
__global__ __launch_bounds__(256, 4) void gemm_kernel(
    const _Float16* __restrict__ H, const int* __restrict__ labels,
    const unsigned char* __restrict__ lab8,
    float* __restrict__ pM, float* __restrict__ pS) {
  __shared__ __align__(16) char ldsB[2][16384];         // B halves [128 cols][64 K] fp16, dbuf
  __shared__ __align__(16) unsigned char ldsLab[1024];  // cg's 1024 col labels

  // XCD-locality swizzle: blocks round-robin XCDs -> cg == XCD (B panel L2-resident)
  int orig = blockIdx.x;                 // 1024 blocks
  int cg = orig & 7;                     // [0,8)
  int strip = orig >> 3;                 // [0,128)

  int tid = threadIdx.x, lane = tid & 63, wave = tid >> 6;
  int wr = wave >> 1, wc = wave & 1;
  int lq = lane >> 4, lr16 = lane & 15;

  // row labels
  int lrw[2];
#pragma unroll
  for (int m = 0; m < 2; ++m)
    lrw[m] = labels[(strip * 64 + wr * 32 + m * 16 + lr16) & (BSZ - 1)];

  // ---- staging source addresses (rule #21: linear LDS dest, inverse-XOR-swizzled source) ----
  uint32_t bgoff[4];
#pragma unroll
  for (int rnd = 0; rnd < 4; ++rnd) {
    int brow = rnd * 32 + wave * 8 + (lane >> 3);
    int cl = (lane & 7) ^ (brow & 7);
    bgoff[rnd] = (uint32_t)(cg * 1024 + brow) * 128 + cl * 8;
  }

  // ---- prologue: A -> buf1 (4 ops), labels -> ldsLab (1 op, 4B/lane), B(it0,kh0) -> buf0 (4 ops) ----
#pragma unroll
  for (int rnd = 0; rnd < 4; ++rnd) {
    int arow = rnd * 16 + wave * 4 + (lane >> 4);
    int cla = (lane & 15) ^ (arow & 7);
    __builtin_amdgcn_global_load_lds(
        (const __attribute__((address_space(1))) void*)(H + (uint32_t)(strip * 64 + arow) * 128 + cla * 8),
        (__attribute__((address_space(3))) void*)(&ldsB[1][rnd * 4096 + wave * 1024]), 16, 0, 0);
  }
  __builtin_amdgcn_global_load_lds(
      (const __attribute__((address_space(1))) void*)(lab8 + cg * 1024 + tid * 4),
      (__attribute__((address_space(3))) void*)(&ldsLab[wave * 256]), 4, 0, 0);

#define STAGE_B(IT, KH, BUF)                                                              \
  {                                                                                       \
    _Pragma("unroll")                                                                     \
    for (int rnd = 0; rnd < 4; ++rnd)                                                     \
      __builtin_amdgcn_global_load_lds(                                                   \
          (const __attribute__((address_space(1))) void*)(H + bgoff[rnd] + (uint32_t)(IT) * 16384 + (KH) * 64), \
          (__attribute__((address_space(3))) void*)(&ldsB[BUF][rnd * 4096 + wave * 1024]), 16, 0, 0); \
  }

  STAGE_B(0, 0, 0);

  // fragment read offsets
  int broff[4], bxr[4];
#pragma unroll
  for (int ni = 0; ni < 4; ++ni) {
    int brow = wc * 64 + ni * 16 + lr16;
    broff[ni] = brow * 128; bxr[ni] = brow & 7;
  }

  // A-loads (queue slots 1-4) complete; lab + B0 stay in flight
  asm volatile("s_waitcnt vmcnt(5)" ::: "memory");
  __builtin_amdgcn_sched_barrier(0);
  __builtin_amdgcn_s_barrier();
  asm volatile("" ::: "memory");

  f16x8 Areg[2][4];
#pragma unroll
  for (int m = 0; m < 2; ++m) {
    int arow = wr * 32 + m * 16 + lr16;
    int axr = arow & 7;
#pragma unroll
    for (int c = 0; c < 4; ++c) {
      f16x8 a = *(const f16x8*)(&ldsB[1][arow * 256 + (((c * 4 + lq) ^ axr) << 4)]);
      Areg[m][c] = a * (_Float16)SCALE2;
    }
  }
  asm volatile("s_waitcnt lgkmcnt(0)" ::: "memory");
  __builtin_amdgcn_sched_barrier(0);
  __builtin_amdgcn_s_barrier();          // buf1 free for STAGE_B(0, kh1)
  asm volatile("" ::: "memory");

  f32x4 acc[2][4];
  float mxv[2] = {-3.0e38f, -3.0e38f}, sv[2] = {0.0f, 0.0f};

#define READB(BUF)                                                                        \
  _Pragma("unroll")                                                                       \
  for (int kk = 0; kk < 2; ++kk)                                                          \
    _Pragma("unroll")                                                                     \
    for (int ni = 0; ni < 4; ++ni)                                                        \
      Bf[kk][ni] = *(const f16x8*)(&ldsB[BUF][broff[ni] + (((kk * 4 + lq) ^ bxr[ni]) << 4)]);

#define MFMAS(KB)                                                                         \
  __builtin_amdgcn_s_setprio(1);                                                          \
  _Pragma("unroll")                                                                       \
  for (int kk = 0; kk < 2; ++kk)                                                          \
    _Pragma("unroll")                                                                     \
    for (int m = 0; m < 2; ++m)                                                           \
      _Pragma("unroll")                                                                   \
      for (int ni = 0; ni < 4; ++ni)                                                      \
        acc[m][ni] = __builtin_amdgcn_mfma_f32_16x16x32_f16(Bf[kk][ni], Areg[m][(KB) + kk], acc[m][ni], 0, 0, 0); \
  __builtin_amdgcn_s_setprio(0);

#pragma unroll 1
  for (int it = 0; it < 8; ++it) {
    // ======== kh = 0 : reads buf0, stages (it, kh1) -> buf1 ========
    STAGE_B(it, 1, 1);
    asm volatile("s_waitcnt vmcnt(4)" ::: "memory");
    __builtin_amdgcn_sched_barrier(0);
    __builtin_amdgcn_s_barrier();
    asm volatile("" ::: "memory");
#pragma unroll
    for (int m = 0; m < 2; ++m)
#pragma unroll
      for (int ni = 0; ni < 4; ++ni) acc[m][ni] = f32x4{0.f, 0.f, 0.f, 0.f};
    {
      f16x8 Bf[2][4];
      READB(0);
      MFMAS(0);
    }
    asm volatile("" ::: "memory");
    __builtin_amdgcn_s_barrier();
    asm volatile("" ::: "memory");

    // ======== kh = 1 : reads buf1, stages (it+1, kh0) -> buf0 ========
    if (it < 7) {
      STAGE_B(it + 1, 0, 0);
      asm volatile("s_waitcnt vmcnt(4)" ::: "memory");
    } else {
      asm volatile("s_waitcnt vmcnt(0)" ::: "memory");
    }
    __builtin_amdgcn_sched_barrier(0);
    __builtin_amdgcn_s_barrier();
    asm volatile("" ::: "memory");
    {
      f16x8 Bf[2][4];
      READB(1);
      MFMAS(2);
    }
    // ---- online epilogue for this 128-col tile (wave-uniform exp-skip) ----
    {
      uint32_t labw[4];
#pragma unroll
      for (int ni = 0; ni < 4; ++ni)
        labw[ni] = *(const uint32_t*)(&ldsLab[it * 128 + wc * 64 + ni * 16 + lq * 4]);
#pragma unroll
      for (int m = 0; m < 2; ++m) {
        float v[16];
#pragma unroll
        for (int ni = 0; ni < 4; ++ni)
#pragma unroll
          for (int reg = 0; reg < 4; ++reg) {
            int lc = (labw[ni] >> (8 * reg)) & 255;
            v[ni * 4 + reg] = (lrw[m] != lc) ? acc[m][ni][reg] : 0.0f;
          }
        float m01 = fmaxf(v[0], v[1]),  m23 = fmaxf(v[2], v[3]);
        float m45 = fmaxf(v[4], v[5]),  m67 = fmaxf(v[6], v[7]);
        float m89 = fmaxf(v[8], v[9]),  mab = fmaxf(v[10], v[11]);
        float mcd = fmaxf(v[12], v[13]), mef = fmaxf(v[14], v[15]);
        float bm = fmaxf(fmaxf(fmaxf(m01, m23), fmaxf(m45, m67)),
                         fmaxf(fmaxf(m89, mab), fmaxf(mcd, mef)));
        // skip if every lane's tile-max is below the exp2 window of its running max:
        // skipped terms < 2^-118 relative to sv -> bit-exact in f32.
        if (__any(bm > mxv[m] - SKIP_THR)) {
          float nm = fmaxf(mxv[m], bm);
          float s0 = 0.f, s1 = 0.f;
#pragma unroll
          for (int i = 0; i < 8; ++i) {
            s0 += exp2f(v[i] - nm);
            s1 += exp2f(v[8 + i] - nm);
          }
          sv[m] = sv[m] * exp2f(mxv[m] - nm) + (s0 + s1);
          mxv[m] = nm;
        }
      }
    }
    asm volatile("" ::: "memory");
    __builtin_amdgcn_s_barrier();
    asm volatile("" ::: "memory");
  }
#undef STAGE_B
#undef READB
#undef MFMAS

  // ---- final reduce: combine lq slices (shfl) then wc halves (LDS, aliased on dead buf0) ----
  float* redM = (float*)ldsB;          // [2][64]
  float* redS = redM + 128;
#pragma unroll
  for (int m = 0; m < 2; ++m) {
    float M = mxv[m], S = sv[m];
#pragma unroll
    for (int off = 16; off < 64; off <<= 1) {
      float Mo = __shfl_xor(M, off, 64);
      float So = __shfl_xor(S, off, 64);
      float Mn = fmaxf(M, Mo);
      S = S * exp2f(M - Mn) + So * exp2f(Mo - Mn);
      M = Mn;
    }
    if (lq == 0) {
      redM[wc * 64 + wr * 32 + m * 16 + lr16] = M;
      redS[wc * 64 + wr * 32 + m * 16 + lr16] = S;
    }
  }
  __syncthreads();
  if (tid < 64) {
    float m0 = redM[tid], m1 = redM[64 + tid];
    float M = fmaxf(m0, m1);
    float S = redS[tid] * exp2f(m0 - M) + redS[64 + tid] * exp2f(m1 - M);
    pM[(size_t)cg * N_TOT + strip * 64 + tid] = M;
    pS[(size_t)cg * N_TOT + strip * 64 + tid] = S;
  }
}

// ---------------- combine 8 chunk-partials per row, partial-sum S per block ----------------
__global__ __launch_bounds__(256) void rowred_kernel(const float* __restrict__ pM,
                                                     const float* __restrict__ pS,
                                                     float* __restrict__ blockS) {
  int row = blockIdx.x * 256 + threadIdx.x;   // 32 blocks x 256 = 8192 rows
  float M = -3.0e38f;
#pragma unroll
  for (int c = 0; c < NCH; ++c) M = fmaxf(M, pM[(size_t)c * N_TOT + row]);
  float s = 0.0f;
#pragma unroll
  for (int c = 0; c < NCH; ++c)
    s += pS[(size_t)c * N_TOT + row] * exp2f(pM[(size_t)c * N_TOT + row] - M);
  __shared__ float red[256];
  red[threadIdx.x] = s;
  __syncthreads();
  for (int st = 128; st > 0; st >>= 1) {
    if (threadIdx.x < st) red[threadIdx.x] += red[threadIdx.x + st];
    __syncthreads();
  }
  if (threadIdx.x == 0) blockS[blockIdx.x] = red[0];
}

// ---------------- final scalar: S, N, validity -> loss ----------------
__global__ void final_kernel(const float* __restrict__ blockS, const int* __restrict__ cnt,
                             float* __restrict__ out) {
  int lane = threadIdx.x;              // 1 wave
  float s = (lane < 32) ? blockS[lane] : 0.0f;
#pragma unroll
  for (int off = 1; off < 64; off <<= 1) s += __shfl_xor(s, off, 64);
  if (lane == 0) {
    double Stot = (double)s;
    long long sumsq = 0;
    int nval = 0;
    for (int c = 0; c < 128; ++c) {
      long long cc = cnt[c];
      sumsq += cc * cc;
      if (cc > 0 && cc < BSZ) nval += 2 * (int)cc;   // valid rows iff not all labels equal
    }
    double Nd = (double)N_TOT * (double)N_TOT - 4.0 * (double)sumsq;
    float loss;
    if (Nd <= 0.0 || nval == 0) {
      loss = logf(1e-6f);              // all_zero branch: xv stays 0 -> log(eps)
    } else {
      float x = (float)(Stot / Nd);
      loss = ((float)nval * logf(x + 1e-6f) +
              (float)(N_TOT - nval) * logf(1e-6f)) / (float)N_TOT;
    }
    out[0] = loss;
  }
}

extern "C" void kernel_launch(void* const* d_in, const int* in_sizes, int n_in,
                              void* d_out, int out_size, void* d_ws, size_t ws_size,
                              hipStream_t stream) {
  const float* feat = (const float*)d_in[0];
  const int* labels = (const int*)d_in[1];
  float* out = (float*)d_out;

  char* ws = (char*)d_ws;
  _Float16* H         = (_Float16*)(ws);                 // 8192*128*2 = 2,097,152
  unsigned char* lab8 = (unsigned char*)(ws + 2097152);  // 8,192
  float* pM           = (float*)(ws + 2105344);          // 8*8192*4 = 262,144
  float* pS           = (float*)(ws + 2367488);          // 262,144
  int* cnt            = (int*)(ws + 2629632);            // 512
  float* blockS       = (float*)(ws + 2630144);          // 128

  prep_kernel<<<513, 256, 0, stream>>>(feat, labels, H, lab8, cnt);
  gemm_kernel<<<1024, 256, 0, stream>>>(H, labels, lab8, pM, pS);
  rowred_kernel<<<32, 256, 0, stream>>>(pM, pS, blockS);
  final_kernel<<<1, 64, 0, stream>>>(blockS, cnt, out);
}